// Round 1
// baseline (837.385 us; speedup 1.0000x reference)
//
#include <hip/hip_runtime.h>

#define ETA 0.1f
#define BATCH 4
#define SEQ 2048
#define DMODEL 1024
#define NH 8
#define DHEAD 64
#define HD 512  // NH*DHEAD

typedef float f32x4 __attribute__((ext_vector_type(4)));
typedef short short8 __attribute__((ext_vector_type(8)));

static __device__ __forceinline__ ushort f2bf(float f) {
  union { float f; unsigned u; } x; x.f = f;
  unsigned r = (x.u + 0x7fffu + ((x.u >> 16) & 1u)) >> 16;
  return (ushort)r;
}

// C[M,Nc] = A[M,K] @ B[K,Nc] (+bias), f32 in/out, bf16 MFMA compute.
// 64x64 tile, BK=32, 256 threads (4 waves), wave w owns rows [16w,16w+16).
__global__ __launch_bounds__(256) void gemm_bf16_kernel(
    const float* __restrict__ A, const float* __restrict__ B,
    float* __restrict__ C, const float* __restrict__ bias,
    int M, int Nc, int K) {
  const int tiles_n = Nc >> 6;
  const int bm = blockIdx.x / tiles_n;
  const int bn = blockIdx.x % tiles_n;
  const int tid = threadIdx.x;
  const int w = tid >> 6, lane = tid & 63;

  __shared__ ushort As[64][40];  // [row][k], +8 pad (stride 80B)
  __shared__ ushort Bs[64][40];  // [col][k] (B transposed), +8 pad

  f32x4 acc[4];
#pragma unroll
  for (int c = 0; c < 4; ++c) acc[c] = f32x4{0.f, 0.f, 0.f, 0.f};

  const int frow = lane & 15;        // fragment row/col within 16
  const int fk = (lane >> 4) * 8;    // k-base within 32

  for (int kt = 0; kt < K; kt += 32) {
    // stage A tile: 64 rows x 32 k, f32 -> bf16
#pragma unroll
    for (int s = 0; s < 2; ++s) {
      int idx = tid + (s << 8);          // 0..511 float4s
      int r = idx >> 3, c4 = (idx & 7) << 2;
      f32x4 val = *(const f32x4*)&A[(size_t)(bm * 64 + r) * K + kt + c4];
      As[r][c4 + 0] = f2bf(val[0]);
      As[r][c4 + 1] = f2bf(val[1]);
      As[r][c4 + 2] = f2bf(val[2]);
      As[r][c4 + 3] = f2bf(val[3]);
    }
    // stage B tile transposed: global [k][n] -> Bs[n][k]
#pragma unroll
    for (int s = 0; s < 2; ++s) {
      int idx = tid + (s << 8);
      int kk = idx >> 4, n4 = (idx & 15) << 2;
      f32x4 val = *(const f32x4*)&B[(size_t)(kt + kk) * Nc + bn * 64 + n4];
      Bs[n4 + 0][kk] = f2bf(val[0]);
      Bs[n4 + 1][kk] = f2bf(val[1]);
      Bs[n4 + 2][kk] = f2bf(val[2]);
      Bs[n4 + 3][kk] = f2bf(val[3]);
    }
    __syncthreads();
    short8 af = *(const short8*)&As[w * 16 + frow][fk];
#pragma unroll
    for (int c = 0; c < 4; ++c) {
      short8 bf = *(const short8*)&Bs[c * 16 + frow][fk];
      acc[c] = __builtin_amdgcn_mfma_f32_16x16x32_bf16(af, bf, acc[c], 0, 0, 0);
    }
    __syncthreads();
  }
  // epilogue: C/D layout col=lane&15, row=(lane>>4)*4+reg
#pragma unroll
  for (int c = 0; c < 4; ++c) {
    int gc = bn * 64 + c * 16 + (lane & 15);
    float badd = bias ? bias[gc] : 0.f;
#pragma unroll
    for (int r = 0; r < 4; ++r) {
      int gr = bm * 64 + w * 16 + (lane >> 4) * 4 + r;
      C[(size_t)gr * Nc + gc] = acc[c][r] + badd;
    }
  }
}

// Sequential Hebbian scan. One block per (b,h); 256 threads.
// Thread (w,lane): row i = 16w + (lane>>2), owns cols [16*(lane&3), +16).
// st[i,j] = d_t*st[i,j] + ETA*k_i*v_j ; y_i = sum_j st[i,j]*q_j
__global__ __launch_bounds__(256) void scan_kernel(
    const float* __restrict__ q, const float* __restrict__ k,
    const float* __restrict__ v, const float* __restrict__ gamma,
    const float* __restrict__ state0, float* __restrict__ y,
    float* __restrict__ state_out) {
  const int bh = blockIdx.x;
  const int b = bh >> 3, h = bh & 7;
  const int tid = threadIdx.x;
  const int w = tid >> 6, lane = tid & 63;
  const int i = w * 16 + (lane >> 2);
  const int jg = lane & 3, j0 = jg * 16;

  __shared__ float qs[16][64], ks[16][64], vs[16][64], ys[16][64];
  __shared__ float dc[16];

  float st[16];
  {
    const float* sp = &state0[((size_t)bh * 64 + i) * 64 + j0];
#pragma unroll
    for (int u = 0; u < 4; ++u) {
      f32x4 val = *(const f32x4*)&sp[u * 4];
      st[u * 4 + 0] = val[0]; st[u * 4 + 1] = val[1];
      st[u * 4 + 2] = val[2]; st[u * 4 + 3] = val[3];
    }
  }

  for (int t0 = 0; t0 < SEQ; t0 += 16) {
    // stage 16 steps of q,k,v: 3*16*64 floats, 1 float4/thread/tensor
#pragma unroll
    for (int rr = 0; rr < 3; ++rr) {
      int rem = tid;
      int step = rem >> 4, f4 = (rem & 15) << 2;
      const float* src = rr == 0 ? q : (rr == 1 ? k : v);
      f32x4 val = *(const f32x4*)
          &src[(((size_t)b * SEQ + t0 + step) * NH + h) * 64 + f4];
      float* dst = rr == 0 ? &qs[step][f4] : (rr == 1 ? &ks[step][f4] : &vs[step][f4]);
      *(f32x4*)dst = val;
    }
    if (tid < 16) dc[tid] = expf(-fminf(gamma[(size_t)b * SEQ + t0 + tid], 10.f));
    __syncthreads();

#pragma unroll 4
    for (int t = 0; t < 16; ++t) {
      float d = dc[t];
      float ki = ks[t][i] * ETA;
      float par = 0.f;
#pragma unroll
      for (int u = 0; u < 4; ++u) {
        f32x4 vv = *(const f32x4*)&vs[t][j0 + u * 4];
        f32x4 vq = *(const f32x4*)&qs[t][j0 + u * 4];
#pragma unroll
        for (int e = 0; e < 4; ++e) {
          int jj = u * 4 + e;
          st[jj] = d * st[jj] + ki * vv[e];
          par += st[jj] * vq[e];
        }
      }
      par += __shfl_xor(par, 1);
      par += __shfl_xor(par, 2);
      if (jg == 0) ys[t][i] = par;
    }
    __syncthreads();
    {
      int step = tid >> 4, f4 = (tid & 15) << 2;
      f32x4 val = *(const f32x4*)&ys[step][f4];
      *(f32x4*)&y[(((size_t)b * SEQ + t0 + step) * NH + h) * 64 + f4] = val;
    }
    // next iteration's first __syncthreads orders ys reads vs. rewrites
  }
  {
    float* sp = &state_out[((size_t)bh * 64 + i) * 64 + j0];
#pragma unroll
    for (int u = 0; u < 4; ++u) {
      f32x4 val;
      val[0] = st[u * 4 + 0]; val[1] = st[u * 4 + 1];
      val[2] = st[u * 4 + 2]; val[3] = st[u * 4 + 3];
      *(f32x4*)&sp[u * 4] = val;
    }
  }
}

extern "C" void kernel_launch(void* const* d_in, const int* in_sizes, int n_in,
                              void* d_out, int out_size, void* d_ws, size_t ws_size,
                              hipStream_t stream) {
  const float* x      = (const float*)d_in[0];
  const float* gamma  = (const float*)d_in[1];
  const float* state0 = (const float*)d_in[2];
  const float* Wq     = (const float*)d_in[3];
  const float* Wk     = (const float*)d_in[4];
  const float* Wv     = (const float*)d_in[5];
  const float* Wo     = (const float*)d_in[6];
  const float* bo     = (const float*)d_in[7];

  float* out = (float*)d_out;
  float* state_out = out + (size_t)BATCH * SEQ * DMODEL;

  float* qb = (float*)d_ws;
  float* kb = qb + (size_t)BATCH * SEQ * HD;
  float* vb = kb + (size_t)BATCH * SEQ * HD;
  float* yb = vb + (size_t)BATCH * SEQ * HD;

  const int M = BATCH * SEQ;
  dim3 blk(256);

  gemm_bf16_kernel<<<dim3((M / 64) * (HD / 64)), blk, 0, stream>>>(
      x, Wq, qb, nullptr, M, HD, DMODEL);
  gemm_bf16_kernel<<<dim3((M / 64) * (HD / 64)), blk, 0, stream>>>(
      x, Wk, kb, nullptr, M, HD, DMODEL);
  gemm_bf16_kernel<<<dim3((M / 64) * (HD / 64)), blk, 0, stream>>>(
      x, Wv, vb, nullptr, M, HD, DMODEL);
  scan_kernel<<<dim3(32), blk, 0, stream>>>(qb, kb, vb, gamma, state0, yb, state_out);
  gemm_bf16_kernel<<<dim3((M / 64) * (DMODEL / 64)), blk, 0, stream>>>(
      yb, Wo, out, bo, M, DMODEL, HD);
}

// Round 2
// 303.281 us; speedup vs baseline: 2.7611x; 2.7611x over previous
//
#include <hip/hip_runtime.h>

#define ETA 0.1f
#define BATCH 4
#define SEQ 2048
#define DMODEL 1024
#define NH 8
#define DHEAD 64
#define HD 512   // NH*DHEAD
#define CH 64    // chunk length
#define NCH (SEQ / CH)  // 32

typedef float f32x4 __attribute__((ext_vector_type(4)));
typedef short short8 __attribute__((ext_vector_type(8)));

static __device__ __forceinline__ ushort f2bf(float f) {
  union { float f; unsigned u; } x; x.f = f;
  unsigned r = (x.u + 0x7fffu + ((x.u >> 16) & 1u)) >> 16;
  return (ushort)r;
}

// ---------------------------------------------------------------------------
// GEMM: C[M,Nc] = A[M,K] @ B[K,Nc] (+bias), f32 in/out, bf16 MFMA compute.
// 64x64 tile, BK=32, 256 threads (4 waves).
// ---------------------------------------------------------------------------
__global__ __launch_bounds__(256) void gemm_bf16_kernel(
    const float* __restrict__ A, const float* __restrict__ B,
    float* __restrict__ C, const float* __restrict__ bias,
    int M, int Nc, int K) {
  const int tiles_n = Nc >> 6;
  const int bm = blockIdx.x / tiles_n;
  const int bn = blockIdx.x % tiles_n;
  const int tid = threadIdx.x;
  const int w = tid >> 6, lane = tid & 63;

  __shared__ ushort As[64][40];
  __shared__ ushort Bs[64][40];

  f32x4 acc[4];
#pragma unroll
  for (int c = 0; c < 4; ++c) acc[c] = f32x4{0.f, 0.f, 0.f, 0.f};

  const int frow = lane & 15;
  const int fk = (lane >> 4) * 8;

  for (int kt = 0; kt < K; kt += 32) {
#pragma unroll
    for (int s = 0; s < 2; ++s) {
      int idx = tid + (s << 8);
      int r = idx >> 3, c4 = (idx & 7) << 2;
      f32x4 val = *(const f32x4*)&A[(size_t)(bm * 64 + r) * K + kt + c4];
      As[r][c4 + 0] = f2bf(val[0]);
      As[r][c4 + 1] = f2bf(val[1]);
      As[r][c4 + 2] = f2bf(val[2]);
      As[r][c4 + 3] = f2bf(val[3]);
    }
#pragma unroll
    for (int s = 0; s < 2; ++s) {
      int idx = tid + (s << 8);
      int kk = idx >> 4, n4 = (idx & 15) << 2;
      f32x4 val = *(const f32x4*)&B[(size_t)(kt + kk) * Nc + bn * 64 + n4];
      Bs[n4 + 0][kk] = f2bf(val[0]);
      Bs[n4 + 1][kk] = f2bf(val[1]);
      Bs[n4 + 2][kk] = f2bf(val[2]);
      Bs[n4 + 3][kk] = f2bf(val[3]);
    }
    __syncthreads();
    short8 af = *(const short8*)&As[w * 16 + frow][fk];
#pragma unroll
    for (int c = 0; c < 4; ++c) {
      short8 bf = *(const short8*)&Bs[c * 16 + frow][fk];
      acc[c] = __builtin_amdgcn_mfma_f32_16x16x32_bf16(af, bf, acc[c], 0, 0, 0);
    }
    __syncthreads();
  }
#pragma unroll
  for (int c = 0; c < 4; ++c) {
    int gc = bn * 64 + c * 16 + (lane & 15);
    float badd = bias ? bias[gc] : 0.f;
#pragma unroll
    for (int r = 0; r < 4; ++r) {
      int gr = bm * 64 + w * 16 + (lane >> 4) * 4 + r;
      C[(size_t)gr * Nc + gc] = acc[c][r] + badd;
    }
  }
}

// ---------------------------------------------------------------------------
// Phase 1 (intra-chunk, fully parallel over (b,h,chunk)):
//   cum[p]   = prod_{r<=p} d_{c*64+r}   (inclusive decay within chunk)
//   Ah       = (cum*q) @ (v/cum)^T, mask s<=p, * ETA  -> P (bf16)
//   Y_intra  = P @ K
//   S_c      = ETA*cl * K^T @ (V/cum)   (chunk's additive state contribution)
// ---------------------------------------------------------------------------
__global__ __launch_bounds__(256) void intra_kernel(
    const float* __restrict__ q, const float* __restrict__ k,
    const float* __restrict__ v, const float* __restrict__ gamma,
    float* __restrict__ y, float* __restrict__ S, float* __restrict__ clb) {
  const int bx = blockIdx.x;
  const int c = bx & (NCH - 1);
  const int h = (bx >> 5) & (NH - 1);
  const int b = bx >> 8;
  const int tid = threadIdx.x;
  const int w = tid >> 6, lane = tid & 63;
  const int fr = lane & 15, fq = lane >> 4;

  __shared__ ushort Qs[64][72];   // [p][dh]  cum[p]*q
  __shared__ ushort Vs[64][72];   // [s][dh]  v/cum[s]
  __shared__ ushort KT[64][72];   // [dh][s]  k transposed
  __shared__ ushort VT[64][72];   // [dh][s]  (v/cum) transposed
  __shared__ ushort Ps[64][72];   // [p][s]   masked scores (bf16)
  __shared__ float cumS[64];
  __shared__ float clS;

  // ---- global loads: one row-quarter (16 floats) of q/k/v per thread
  const int p = tid >> 2, d0 = (tid & 3) * 16;
  const size_t rb = (((size_t)b * SEQ + c * CH + p) * NH + h) * DHEAD + d0;
  f32x4 qr[4], kr[4], vr[4];
#pragma unroll
  for (int u = 0; u < 4; ++u) {
    qr[u] = *(const f32x4*)&q[rb + u * 4];
    kr[u] = *(const f32x4*)&k[rb + u * 4];
    vr[u] = *(const f32x4*)&v[rb + u * 4];
  }

  // ---- inclusive prefix product of decay (wave 0)
  if (tid < 64) {
    float g = gamma[(size_t)b * SEQ + c * CH + tid];
    float prod = expf(-fminf(g, 10.f));
#pragma unroll
    for (int off = 1; off < 64; off <<= 1) {
      float o = __shfl_up(prod, off);
      if (tid >= off) prod *= o;
    }
    cumS[tid] = prod;
    if (tid == 63) clS = prod;
  }
  __syncthreads();

  // ---- stage to LDS (f32 -> bf16 with decay scalings)
  {
    const float cp = cumS[p];
    const float rc = 1.f / cp;
    ushort tq[16], tv[16];
#pragma unroll
    for (int u = 0; u < 4; ++u) {
#pragma unroll
      for (int e = 0; e < 4; ++e) {
        int j = u * 4 + e;
        tq[j] = f2bf(qr[u][e] * cp);
        tv[j] = f2bf(vr[u][e] * rc);
        KT[d0 + j][p] = f2bf(kr[u][e]);
        VT[d0 + j][p] = tv[j];
      }
    }
    *(short8*)&Qs[p][d0] = *(short8*)&tq[0];
    *(short8*)&Qs[p][d0 + 8] = *(short8*)&tq[8];
    *(short8*)&Vs[p][d0] = *(short8*)&tv[0];
    *(short8*)&Vs[p][d0 + 8] = *(short8*)&tv[8];
  }
  __syncthreads();

  // ---- mm1: Ah[p][s], mask s<=p, write P
  const int arow = w * 16 + fr;
  {
    short8 a0 = *(const short8*)&Qs[arow][fq * 8];
    short8 a1 = *(const short8*)&Qs[arow][32 + fq * 8];
#pragma unroll
    for (int cf = 0; cf < 4; ++cf) {
      f32x4 acc = {0.f, 0.f, 0.f, 0.f};
      if (cf <= w) {
        short8 b0 = *(const short8*)&Vs[cf * 16 + fr][fq * 8];
        short8 b1 = *(const short8*)&Vs[cf * 16 + fr][32 + fq * 8];
        acc = __builtin_amdgcn_mfma_f32_16x16x32_bf16(a0, b0, acc, 0, 0, 0);
        acc = __builtin_amdgcn_mfma_f32_16x16x32_bf16(a1, b1, acc, 0, 0, 0);
      }
#pragma unroll
      for (int r = 0; r < 4; ++r) {
        int pi = w * 16 + fq * 4 + r, si = cf * 16 + fr;
        Ps[pi][si] = f2bf((si <= pi) ? acc[r] * ETA : 0.f);
      }
    }
  }
  __syncthreads();

  // ---- mm3: Y_intra = P @ K ; mm4: S_c = (ETA*cl) * K^T @ (V/cum)
  {
    short8 p0 = *(const short8*)&Ps[arow][fq * 8];
    short8 p1 = *(const short8*)&Ps[arow][32 + fq * 8];
    short8 ka0 = *(const short8*)&KT[arow][fq * 8];
    short8 ka1 = *(const short8*)&KT[arow][32 + fq * 8];
    const float scl = ETA * clS;
    const size_t ybase = (((size_t)b * SEQ + c * CH) * NH + h) * DHEAD;
    float* Sp = &S[(((size_t)(b * NH + h)) * NCH + c) << 12];
#pragma unroll
    for (int cf = 0; cf < 4; ++cf) {
      short8 bk0 = *(const short8*)&KT[cf * 16 + fr][fq * 8];
      short8 bk1 = *(const short8*)&KT[cf * 16 + fr][32 + fq * 8];
      f32x4 accY = {0.f, 0.f, 0.f, 0.f};
      accY = __builtin_amdgcn_mfma_f32_16x16x32_bf16(p0, bk0, accY, 0, 0, 0);
      accY = __builtin_amdgcn_mfma_f32_16x16x32_bf16(p1, bk1, accY, 0, 0, 0);
      short8 bv0 = *(const short8*)&VT[cf * 16 + fr][fq * 8];
      short8 bv1 = *(const short8*)&VT[cf * 16 + fr][32 + fq * 8];
      f32x4 accS = {0.f, 0.f, 0.f, 0.f};
      accS = __builtin_amdgcn_mfma_f32_16x16x32_bf16(ka0, bv0, accS, 0, 0, 0);
      accS = __builtin_amdgcn_mfma_f32_16x16x32_bf16(ka1, bv1, accS, 0, 0, 0);
#pragma unroll
      for (int r = 0; r < 4; ++r) {
        int row = w * 16 + fq * 4 + r;
        int col = cf * 16 + fr;
        y[ybase + (size_t)row * HD + col] = accY[r];
        Sp[row * 64 + col] = accS[r] * scl;
      }
    }
  }
  if (tid == 0 && h == 0) clb[b * NCH + c] = clS;
}

// ---------------------------------------------------------------------------
// Phase 2 (serial over chunks; parallel over (b,h,row-group)):
//   stash[c] = st (state BEFORE chunk c); st = cl[c]*st + S_c
// ---------------------------------------------------------------------------
__global__ __launch_bounds__(256) void prop_kernel(
    const float* __restrict__ state0, const float* __restrict__ S,
    const float* __restrict__ clb, float* __restrict__ stash,
    float* __restrict__ state_out) {
  const int bh = blockIdx.x >> 2, rg = blockIdx.x & 3;
  const int b = bh >> 3;
  const int tid = threadIdx.x;
  const int i = rg * 16 + (tid >> 4);
  const int j0 = (tid & 15) * 4;
  const size_t off = ((size_t)bh * 64 + i) * 64 + j0;
  const size_t coff = (size_t)i * 64 + j0;

  f32x4 st = *(const f32x4*)&state0[off];
#pragma unroll 4
  for (int c = 0; c < NCH; ++c) {
    const size_t base = (((size_t)bh * NCH + c) << 12) + coff;
    *(f32x4*)&stash[base] = st;
    f32x4 s = *(const f32x4*)&S[base];
    float clv = clb[b * NCH + c];
    st = st * clv + s;
  }
  *(f32x4*)&state_out[off] = st;
}

// ---------------------------------------------------------------------------
// Phase 3 (parallel over (b,h,chunk)):  y += (cum*q) @ st_prev^T
// ---------------------------------------------------------------------------
__global__ __launch_bounds__(256) void inter_kernel(
    const float* __restrict__ q, const float* __restrict__ gamma,
    const float* __restrict__ stash, float* __restrict__ y) {
  const int bx = blockIdx.x;
  const int c = bx & (NCH - 1);
  const int h = (bx >> 5) & (NH - 1);
  const int b = bx >> 8;
  const int tid = threadIdx.x;
  const int w = tid >> 6, lane = tid & 63;
  const int fr = lane & 15, fq = lane >> 4;

  __shared__ ushort Qs[64][72];   // [p][j] cum[p]*q
  __shared__ ushort Bs[64][72];   // [i][j] st_prev (row-major; B-operand reads rows)
  __shared__ float cumS[64];

  const int p = tid >> 2, d0 = (tid & 3) * 16;
  const size_t rb = (((size_t)b * SEQ + c * CH + p) * NH + h) * DHEAD + d0;
  f32x4 qr[4], sr[4];
#pragma unroll
  for (int u = 0; u < 4; ++u) qr[u] = *(const f32x4*)&q[rb + u * 4];
  const size_t sb = ((((size_t)(b * NH + h)) * NCH + c) << 12) + (size_t)p * 64 + d0;
#pragma unroll
  for (int u = 0; u < 4; ++u) sr[u] = *(const f32x4*)&stash[sb + u * 4];

  if (tid < 64) {
    float g = gamma[(size_t)b * SEQ + c * CH + tid];
    float prod = expf(-fminf(g, 10.f));
#pragma unroll
    for (int off = 1; off < 64; off <<= 1) {
      float o = __shfl_up(prod, off);
      if (tid >= off) prod *= o;
    }
    cumS[tid] = prod;
  }
  __syncthreads();

  {
    const float cp = cumS[p];
    ushort tq[16], ts[16];
#pragma unroll
    for (int u = 0; u < 4; ++u) {
#pragma unroll
      for (int e = 0; e < 4; ++e) {
        tq[u * 4 + e] = f2bf(qr[u][e] * cp);
        ts[u * 4 + e] = f2bf(sr[u][e]);
      }
    }
    *(short8*)&Qs[p][d0] = *(short8*)&tq[0];
    *(short8*)&Qs[p][d0 + 8] = *(short8*)&tq[8];
    *(short8*)&Bs[p][d0] = *(short8*)&ts[0];
    *(short8*)&Bs[p][d0 + 8] = *(short8*)&ts[8];
  }
  __syncthreads();

  const int arow = w * 16 + fr;
  short8 a0 = *(const short8*)&Qs[arow][fq * 8];
  short8 a1 = *(const short8*)&Qs[arow][32 + fq * 8];
  const size_t ybase = (((size_t)b * SEQ + c * CH) * NH + h) * DHEAD;
#pragma unroll
  for (int cf = 0; cf < 4; ++cf) {
    short8 b0 = *(const short8*)&Bs[cf * 16 + fr][fq * 8];
    short8 b1 = *(const short8*)&Bs[cf * 16 + fr][32 + fq * 8];
    f32x4 acc = {0.f, 0.f, 0.f, 0.f};
    acc = __builtin_amdgcn_mfma_f32_16x16x32_bf16(a0, b0, acc, 0, 0, 0);
    acc = __builtin_amdgcn_mfma_f32_16x16x32_bf16(a1, b1, acc, 0, 0, 0);
#pragma unroll
    for (int r = 0; r < 4; ++r) {
      int row = w * 16 + fq * 4 + r;
      int col = cf * 16 + fr;
      size_t idx = ybase + (size_t)row * HD + col;
      y[idx] += acc[r];
    }
  }
}

extern "C" void kernel_launch(void* const* d_in, const int* in_sizes, int n_in,
                              void* d_out, int out_size, void* d_ws, size_t ws_size,
                              hipStream_t stream) {
  const float* x      = (const float*)d_in[0];
  const float* gamma  = (const float*)d_in[1];
  const float* state0 = (const float*)d_in[2];
  const float* Wq     = (const float*)d_in[3];
  const float* Wk     = (const float*)d_in[4];
  const float* Wv     = (const float*)d_in[5];
  const float* Wo     = (const float*)d_in[6];
  const float* bo     = (const float*)d_in[7];

  float* out = (float*)d_out;
  float* state_out = out + (size_t)BATCH * SEQ * DMODEL;

  const size_t NBH = (size_t)BATCH * SEQ * HD;  // 4,194,304
  float* qb    = (float*)d_ws;
  float* kb    = qb + NBH;
  float* vb    = kb + NBH;
  float* yb    = vb + NBH;
  float* Sb    = yb + NBH;
  float* stash = Sb + NBH;
  float* clb   = stash + NBH;

  const int M = BATCH * SEQ;
  dim3 blk(256);

  gemm_bf16_kernel<<<dim3((M / 64) * (HD / 64)), blk, 0, stream>>>(
      x, Wq, qb, nullptr, M, HD, DMODEL);
  gemm_bf16_kernel<<<dim3((M / 64) * (HD / 64)), blk, 0, stream>>>(
      x, Wk, kb, nullptr, M, HD, DMODEL);
  gemm_bf16_kernel<<<dim3((M / 64) * (HD / 64)), blk, 0, stream>>>(
      x, Wv, vb, nullptr, M, HD, DMODEL);

  intra_kernel<<<dim3(BATCH * NH * NCH), blk, 0, stream>>>(
      qb, kb, vb, gamma, yb, Sb, clb);
  prop_kernel<<<dim3(BATCH * NH * 4), blk, 0, stream>>>(
      state0, Sb, clb, stash, state_out);
  inter_kernel<<<dim3(BATCH * NH * NCH), blk, 0, stream>>>(
      qb, gamma, stash, yb);

  gemm_bf16_kernel<<<dim3((M / 64) * (DMODEL / 64)), blk, 0, stream>>>(
      yb, Wo, out, bo, M, DMODEL, HD);
}

// Round 3
// 100.172 us; speedup vs baseline: 8.3594x; 3.0276x over previous
//
#include <hip/hip_runtime.h>

#define ETA 0.1f
#define BATCH 4
#define SEQ 2048
#define DMODEL 1024
#define NH 8
#define DHEAD 64
#define HD 512   // NH*DHEAD
#define QKVW 1536
#define CH 64    // chunk length
#define NCH (SEQ / CH)  // 32

typedef float f32x4 __attribute__((ext_vector_type(4)));
typedef short short8 __attribute__((ext_vector_type(8)));
typedef short short4v __attribute__((ext_vector_type(4)));

static __device__ __forceinline__ ushort f2bf(float f) {
  union { float f; unsigned u; } x; x.f = f;
  unsigned r = (x.u + 0x7fffu + ((x.u >> 16) & 1u)) >> 16;
  return (ushort)r;
}
static __device__ __forceinline__ float bf2f(ushort u) {
  union { unsigned u; float f; } x; x.u = ((unsigned)u) << 16;
  return x.f;
}

#define GLDS16(g, l)                                                    \
  __builtin_amdgcn_global_load_lds(                                     \
      (const __attribute__((address_space(1))) unsigned int*)(const void*)(g), \
      (__attribute__((address_space(3))) unsigned int*)(void*)(l), 16, 0, 0)

// ---------------------------------------------------------------------------
// convx: f32 -> bf16 straight copy (x). 8192*1024 elems, 16/thread.
// ---------------------------------------------------------------------------
__global__ __launch_bounds__(256) void convx_kernel(
    const float* __restrict__ x, ushort* __restrict__ xb) {
  size_t i = ((size_t)blockIdx.x * 256 + threadIdx.x) * 16;
  ushort t[16];
#pragma unroll
  for (int u = 0; u < 4; ++u) {
    f32x4 v = *(const f32x4*)&x[i + u * 4];
#pragma unroll
    for (int e = 0; e < 4; ++e) t[u * 4 + e] = f2bf(v[e]);
  }
  *(short8*)&xb[i] = *(short8*)&t[0];
  *(short8*)&xb[i + 8] = *(short8*)&t[8];
}

// ---------------------------------------------------------------------------
// convw: transpose + convert weights.
//   blockIdx.y 0..2: Wq/Wk/Wv [1024][512] -> Wt rows [y*512 + n][k] (stride 1024)
//   blockIdx.y 3   : Wo [512][1024] -> Wot [n][k] (stride 512)
// 32x32 tiles, 256 threads.
// ---------------------------------------------------------------------------
__global__ __launch_bounds__(256) void convw_kernel(
    const float* __restrict__ Wq, const float* __restrict__ Wk,
    const float* __restrict__ Wv, const float* __restrict__ Wo,
    ushort* __restrict__ Wt, ushort* __restrict__ Wot) {
  const int m = blockIdx.y;
  const int bx = blockIdx.x;
  const int tid = threadIdx.x;
  __shared__ float T[32][33];

  const float* src;
  ushort* dst;
  int srcN, dstK, k0, n0, rowOff;
  if (m < 3) {
    src = (m == 0) ? Wq : ((m == 1) ? Wk : Wv);
    srcN = 512; dstK = 1024;
    k0 = (bx >> 4) << 5; n0 = (bx & 15) << 5;
    dst = Wt; rowOff = m * 512;
  } else {
    src = Wo; srcN = 1024; dstK = 512;
    k0 = (bx >> 5) << 5; n0 = (bx & 31) << 5;
    dst = Wot; rowOff = 0;
  }
  const int r = tid >> 3, c4 = (tid & 7) << 2;
  f32x4 v = *(const f32x4*)&src[(size_t)(k0 + r) * srcN + n0 + c4];
  T[r][c4 + 0] = v[0]; T[r][c4 + 1] = v[1];
  T[r][c4 + 2] = v[2]; T[r][c4 + 3] = v[3];
  __syncthreads();
  short4v o;
#pragma unroll
  for (int e = 0; e < 4; ++e) o[e] = (short)f2bf(T[c4 + e][r]);
  *(short4v*)&dst[(size_t)(rowOff + n0 + r) * dstK + k0 + c4] = o;
}

// ---------------------------------------------------------------------------
// GEMM (m97 structure): C[M][N] = A[M][K] @ Bt[N][K]^T, bf16 inputs.
// 128x128 tile, BK=32, 256 threads, global_load_lds(16B), double-buffered
// LDS with 2-phase schedule. OUT_BF16: C bf16; else C f32 (+bias).
// ---------------------------------------------------------------------------
template <bool OUT_BF16>
__global__ __launch_bounds__(256) void gemm_bt_kernel(
    const ushort* __restrict__ A, const ushort* __restrict__ Bt,
    void* __restrict__ Cv, const float* __restrict__ bias,
    int M, int N, int K) {
  const int tiles_n = N >> 7;
  const int bm = blockIdx.x / tiles_n;
  const int bn = blockIdx.x % tiles_n;
  const int tid = threadIdx.x;
  const int w = tid >> 6, lane = tid & 63;
  const int wr = w >> 1, wc = w & 1;
  const int fr = lane & 15, fq = lane >> 4;

  __shared__ ushort As[2][128][32];
  __shared__ ushort Bs[2][128][32];

  f32x4 acc[4][4];
#pragma unroll
  for (int mi = 0; mi < 4; ++mi)
#pragma unroll
    for (int ni = 0; ni < 4; ++ni) acc[mi][ni] = f32x4{0.f, 0.f, 0.f, 0.f};

  const int lw = lane >> 2;            // row within 16-row group
  const int lc = (lane & 3) << 3;      // ushort col (8 bf16 = 16B)
  const ushort* ga = A + (size_t)(bm * 128 + w * 32 + lw) * K + lc;
  const ushort* gb = Bt + (size_t)(bn * 128 + w * 32 + lw) * K + lc;
  const size_t rstep = (size_t)16 * K;

  const int nt = K >> 5;

  // prologue: stage tile 0 into buffer 0
  {
    ushort* la = &As[0][w * 32][0];
    ushort* lb = &Bs[0][w * 32][0];
    GLDS16(ga, la);
    GLDS16(ga + rstep, la + 16 * 32);
    GLDS16(gb, lb);
    GLDS16(gb + rstep, lb + 16 * 32);
  }
  asm volatile("s_waitcnt vmcnt(0)" ::: "memory");
  __syncthreads();

  for (int t = 0; t < nt; ++t) {
    if (t + 1 < nt) {
      const int nb = (t + 1) & 1;
      const int kt = (t + 1) << 5;
      ushort* la = &As[nb][w * 32][0];
      ushort* lb = &Bs[nb][w * 32][0];
      GLDS16(ga + kt, la);
      GLDS16(ga + kt + rstep, la + 16 * 32);
      GLDS16(gb + kt, lb);
      GLDS16(gb + kt + rstep, lb + 16 * 32);
    }
    const int cb = t & 1;
    short8 a[4], b[4];
#pragma unroll
    for (int mi = 0; mi < 4; ++mi)
      a[mi] = *(const short8*)&As[cb][wr * 64 + mi * 16 + fr][fq * 8];
#pragma unroll
    for (int ni = 0; ni < 4; ++ni)
      b[ni] = *(const short8*)&Bs[cb][wc * 64 + ni * 16 + fr][fq * 8];
#pragma unroll
    for (int mi = 0; mi < 4; ++mi)
#pragma unroll
      for (int ni = 0; ni < 4; ++ni)
        acc[mi][ni] = __builtin_amdgcn_mfma_f32_16x16x32_bf16(
            a[mi], b[ni], acc[mi][ni], 0, 0, 0);
    asm volatile("s_waitcnt vmcnt(0)" ::: "memory");
    __syncthreads();
  }

  // epilogue: C/D layout col=lane&15, row=(lane>>4)*4+reg
#pragma unroll
  for (int ni = 0; ni < 4; ++ni) {
    const int gc = bn * 128 + wc * 64 + ni * 16 + fr;
    float badd = (!OUT_BF16 && bias) ? bias[gc] : 0.f;
#pragma unroll
    for (int mi = 0; mi < 4; ++mi) {
#pragma unroll
      for (int r = 0; r < 4; ++r) {
        const int gr = bm * 128 + wr * 64 + mi * 16 + fq * 4 + r;
        if (OUT_BF16) {
          ((ushort*)Cv)[(size_t)gr * N + gc] = f2bf(acc[mi][ni][r]);
        } else {
          ((float*)Cv)[(size_t)gr * N + gc] = acc[mi][ni][r] + badd;
        }
      }
    }
  }
}

// ---------------------------------------------------------------------------
// Phase 1 (intra-chunk): reads fused bf16 qkv [M][1536].
//   cum[p] = prod_{r<=p} d ;  P = mask(cum*q @ (v/cum)^T)*ETA (bf16)
//   y_intra = P @ K (bf16 out);  S_c = ETA*cl * K^T @ (V/cum) (f32)
// ---------------------------------------------------------------------------
__global__ __launch_bounds__(256) void intra_kernel(
    const ushort* __restrict__ qkv, const float* __restrict__ gamma,
    ushort* __restrict__ ybf, float* __restrict__ S, float* __restrict__ clb) {
  const int bx = blockIdx.x;
  const int c = bx & (NCH - 1);
  const int h = (bx >> 5) & (NH - 1);
  const int b = bx >> 8;
  const int tid = threadIdx.x;
  const int w = tid >> 6, lane = tid & 63;
  const int fr = lane & 15, fq = lane >> 4;

  __shared__ ushort Qs[64][72];
  __shared__ ushort Vs[64][72];
  __shared__ ushort KT[64][72];
  __shared__ ushort VT[64][72];
  __shared__ ushort Ps[64][72];
  __shared__ float cumS[64];
  __shared__ float clS;

  const int p = tid >> 2, d0 = (tid & 3) * 16;
  const ushort* base = &qkv[((size_t)b * SEQ + c * CH + p) * QKVW + h * 64 + d0];
  short8 q0 = *(const short8*)base;
  short8 q1 = *(const short8*)(base + 8);
  short8 k0 = *(const short8*)(base + 512);
  short8 k1 = *(const short8*)(base + 520);
  short8 v0 = *(const short8*)(base + 1024);
  short8 v1 = *(const short8*)(base + 1032);

  if (tid < 64) {
    float g = gamma[(size_t)b * SEQ + c * CH + tid];
    float prod = expf(-fminf(g, 10.f));
#pragma unroll
    for (int off = 1; off < 64; off <<= 1) {
      float o = __shfl_up(prod, off);
      if (tid >= off) prod *= o;
    }
    cumS[tid] = prod;
    if (tid == 63) clS = prod;
  }
  __syncthreads();

  {
    const float cp = cumS[p];
    const float rc = 1.f / cp;
    ushort tq[16], tv[16];
#pragma unroll
    for (int j = 0; j < 8; ++j) {
      tq[j]     = f2bf(bf2f((ushort)q0[j]) * cp);
      tq[8 + j] = f2bf(bf2f((ushort)q1[j]) * cp);
      tv[j]     = f2bf(bf2f((ushort)v0[j]) * rc);
      tv[8 + j] = f2bf(bf2f((ushort)v1[j]) * rc);
      KT[d0 + j][p] = (ushort)k0[j];
      KT[d0 + 8 + j][p] = (ushort)k1[j];
      VT[d0 + j][p] = tv[j];
      VT[d0 + 8 + j][p] = tv[8 + j];
    }
    *(short8*)&Qs[p][d0] = *(short8*)&tq[0];
    *(short8*)&Qs[p][d0 + 8] = *(short8*)&tq[8];
    *(short8*)&Vs[p][d0] = *(short8*)&tv[0];
    *(short8*)&Vs[p][d0 + 8] = *(short8*)&tv[8];
  }
  __syncthreads();

  const int arow = w * 16 + fr;
  {
    short8 a0 = *(const short8*)&Qs[arow][fq * 8];
    short8 a1 = *(const short8*)&Qs[arow][32 + fq * 8];
#pragma unroll
    for (int cf = 0; cf < 4; ++cf) {
      f32x4 acc = {0.f, 0.f, 0.f, 0.f};
      if (cf <= w) {
        short8 b0 = *(const short8*)&Vs[cf * 16 + fr][fq * 8];
        short8 b1 = *(const short8*)&Vs[cf * 16 + fr][32 + fq * 8];
        acc = __builtin_amdgcn_mfma_f32_16x16x32_bf16(a0, b0, acc, 0, 0, 0);
        acc = __builtin_amdgcn_mfma_f32_16x16x32_bf16(a1, b1, acc, 0, 0, 0);
      }
#pragma unroll
      for (int r = 0; r < 4; ++r) {
        int pi = w * 16 + fq * 4 + r, si = cf * 16 + fr;
        Ps[pi][si] = f2bf((si <= pi) ? acc[r] * ETA : 0.f);
      }
    }
  }
  __syncthreads();

  {
    short8 p0 = *(const short8*)&Ps[arow][fq * 8];
    short8 p1 = *(const short8*)&Ps[arow][32 + fq * 8];
    short8 ka0 = *(const short8*)&KT[arow][fq * 8];
    short8 ka1 = *(const short8*)&KT[arow][32 + fq * 8];
    const float scl = ETA * clS;
    const size_t yrow0 = (size_t)b * SEQ + c * CH;
    float* Sp = &S[(((size_t)(b * NH + h)) * NCH + c) << 12];
#pragma unroll
    for (int cf = 0; cf < 4; ++cf) {
      short8 bk0 = *(const short8*)&KT[cf * 16 + fr][fq * 8];
      short8 bk1 = *(const short8*)&KT[cf * 16 + fr][32 + fq * 8];
      f32x4 accY = {0.f, 0.f, 0.f, 0.f};
      accY = __builtin_amdgcn_mfma_f32_16x16x32_bf16(p0, bk0, accY, 0, 0, 0);
      accY = __builtin_amdgcn_mfma_f32_16x16x32_bf16(p1, bk1, accY, 0, 0, 0);
      short8 bv0 = *(const short8*)&VT[cf * 16 + fr][fq * 8];
      short8 bv1 = *(const short8*)&VT[cf * 16 + fr][32 + fq * 8];
      f32x4 accS = {0.f, 0.f, 0.f, 0.f};
      accS = __builtin_amdgcn_mfma_f32_16x16x32_bf16(ka0, bv0, accS, 0, 0, 0);
      accS = __builtin_amdgcn_mfma_f32_16x16x32_bf16(ka1, bv1, accS, 0, 0, 0);
#pragma unroll
      for (int r = 0; r < 4; ++r) {
        int row = w * 16 + fq * 4 + r;
        int col = cf * 16 + fr;
        ybf[(yrow0 + row) * HD + h * 64 + col] = f2bf(accY[r]);
        Sp[row * 64 + col] = accS[r] * scl;
      }
    }
  }
  if (tid == 0 && h == 0) clb[b * NCH + c] = clS;
}

// ---------------------------------------------------------------------------
// Phase 2: stash[c] = st (before chunk c); st = cl[c]*st + S_c
// ---------------------------------------------------------------------------
__global__ __launch_bounds__(256) void prop_kernel(
    const float* __restrict__ state0, const float* __restrict__ S,
    const float* __restrict__ clb, float* __restrict__ stash,
    float* __restrict__ state_out) {
  const int bh = blockIdx.x >> 2, rg = blockIdx.x & 3;
  const int b = bh >> 3;
  const int tid = threadIdx.x;
  const int i = rg * 16 + (tid >> 4);
  const int j0 = (tid & 15) * 4;
  const size_t off = ((size_t)bh * 64 + i) * 64 + j0;
  const size_t coff = (size_t)i * 64 + j0;

  f32x4 st = *(const f32x4*)&state0[off];
#pragma unroll 4
  for (int c = 0; c < NCH; ++c) {
    const size_t base = (((size_t)bh * NCH + c) << 12) + coff;
    *(f32x4*)&stash[base] = st;
    f32x4 s = *(const f32x4*)&S[base];
    float clv = clb[b * NCH + c];
    st = st * clv + s;
  }
  *(f32x4*)&state_out[off] = st;
}

// ---------------------------------------------------------------------------
// Phase 3: y += (cum*q) @ st_prev^T   (bf16 read-modify-write on y)
// ---------------------------------------------------------------------------
__global__ __launch_bounds__(256) void inter_kernel(
    const ushort* __restrict__ qkv, const float* __restrict__ gamma,
    const float* __restrict__ stash, ushort* __restrict__ ybf) {
  const int bx = blockIdx.x;
  const int c = bx & (NCH - 1);
  const int h = (bx >> 5) & (NH - 1);
  const int b = bx >> 8;
  const int tid = threadIdx.x;
  const int w = tid >> 6, lane = tid & 63;
  const int fr = lane & 15, fq = lane >> 4;

  __shared__ ushort Qs[64][72];
  __shared__ ushort Bs[64][72];
  __shared__ float cumS[64];

  const int p = tid >> 2, d0 = (tid & 3) * 16;
  const ushort* qp = &qkv[((size_t)b * SEQ + c * CH + p) * QKVW + h * 64 + d0];
  short8 q0 = *(const short8*)qp;
  short8 q1 = *(const short8*)(qp + 8);
  const size_t sb = ((((size_t)(b * NH + h)) * NCH + c) << 12) + (size_t)p * 64 + d0;
  f32x4 sr[4];
#pragma unroll
  for (int u = 0; u < 4; ++u) sr[u] = *(const f32x4*)&stash[sb + u * 4];

  if (tid < 64) {
    float g = gamma[(size_t)b * SEQ + c * CH + tid];
    float prod = expf(-fminf(g, 10.f));
#pragma unroll
    for (int off = 1; off < 64; off <<= 1) {
      float o = __shfl_up(prod, off);
      if (tid >= off) prod *= o;
    }
    cumS[tid] = prod;
  }
  __syncthreads();

  {
    const float cp = cumS[p];
    ushort tq[16], ts[16];
#pragma unroll
    for (int j = 0; j < 8; ++j) {
      tq[j]     = f2bf(bf2f((ushort)q0[j]) * cp);
      tq[8 + j] = f2bf(bf2f((ushort)q1[j]) * cp);
    }
#pragma unroll
    for (int u = 0; u < 4; ++u)
#pragma unroll
      for (int e = 0; e < 4; ++e) ts[u * 4 + e] = f2bf(sr[u][e]);
    *(short8*)&Qs[p][d0] = *(short8*)&tq[0];
    *(short8*)&Qs[p][d0 + 8] = *(short8*)&tq[8];
    *(short8*)&Bs[p][d0] = *(short8*)&ts[0];
    *(short8*)&Bs[p][d0 + 8] = *(short8*)&ts[8];
  }
  __syncthreads();

  const int arow = w * 16 + fr;
  short8 a0 = *(const short8*)&Qs[arow][fq * 8];
  short8 a1 = *(const short8*)&Qs[arow][32 + fq * 8];
  const size_t yrow0 = (size_t)b * SEQ + c * CH;
#pragma unroll
  for (int cf = 0; cf < 4; ++cf) {
    short8 b0 = *(const short8*)&Bs[cf * 16 + fr][fq * 8];
    short8 b1 = *(const short8*)&Bs[cf * 16 + fr][32 + fq * 8];
    f32x4 acc = {0.f, 0.f, 0.f, 0.f};
    acc = __builtin_amdgcn_mfma_f32_16x16x32_bf16(a0, b0, acc, 0, 0, 0);
    acc = __builtin_amdgcn_mfma_f32_16x16x32_bf16(a1, b1, acc, 0, 0, 0);
#pragma unroll
    for (int r = 0; r < 4; ++r) {
      int row = w * 16 + fq * 4 + r;
      int col = cf * 16 + fr;
      size_t idx = (yrow0 + row) * HD + h * 64 + col;
      ybf[idx] = f2bf(bf2f(ybf[idx]) + acc[r]);
    }
  }
}

extern "C" void kernel_launch(void* const* d_in, const int* in_sizes, int n_in,
                              void* d_out, int out_size, void* d_ws, size_t ws_size,
                              hipStream_t stream) {
  const float* x      = (const float*)d_in[0];
  const float* gamma  = (const float*)d_in[1];
  const float* state0 = (const float*)d_in[2];
  const float* Wq     = (const float*)d_in[3];
  const float* Wk     = (const float*)d_in[4];
  const float* Wv     = (const float*)d_in[5];
  const float* Wo     = (const float*)d_in[6];
  const float* bo     = (const float*)d_in[7];

  float* out = (float*)d_out;
  float* state_out = out + (size_t)BATCH * SEQ * DMODEL;

  const int M = BATCH * SEQ;  // 8192

  ushort* xb  = (ushort*)d_ws;                       // [8192][1024]
  ushort* wt  = xb + (size_t)M * DMODEL;             // [1536][1024]
  ushort* wot = wt + (size_t)QKVW * DMODEL;          // [1024][512]
  ushort* qkv = wot + (size_t)DMODEL * HD;           // [8192][1536]
  ushort* ybf = qkv + (size_t)M * QKVW;              // [8192][512]
  float*  Sb  = (float*)(ybf + (size_t)M * HD);      // [32][32][4096]
  float* stash = Sb + (size_t)BATCH * NH * NCH * 4096;
  float* clb   = stash + (size_t)BATCH * NH * NCH * 4096;

  dim3 blk(256);

  convx_kernel<<<dim3((M * DMODEL) / (256 * 16)), blk, 0, stream>>>(x, xb);
  convw_kernel<<<dim3(512, 4), blk, 0, stream>>>(Wq, Wk, Wv, Wo, wt, wot);

  gemm_bt_kernel<true><<<dim3((M / 128) * (QKVW / 128)), blk, 0, stream>>>(
      xb, wt, qkv, nullptr, M, QKVW, DMODEL);

  intra_kernel<<<dim3(BATCH * NH * NCH), blk, 0, stream>>>(
      qkv, gamma, ybf, Sb, clb);
  prop_kernel<<<dim3(BATCH * NH * 4), blk, 0, stream>>>(
      state0, Sb, clb, stash, state_out);
  inter_kernel<<<dim3(BATCH * NH * NCH), blk, 0, stream>>>(
      qkv, gamma, stash, ybf);

  gemm_bt_kernel<false><<<dim3((M / 128) * (DMODEL / 128)), blk, 0, stream>>>(
      ybf, wot, out, bo, M, DMODEL, HD);
}

// Round 4
// 99.148 us; speedup vs baseline: 8.4458x; 1.0103x over previous
//
#include <hip/hip_runtime.h>

#define ETA 0.1f
#define BATCH 4
#define SEQ 2048
#define DMODEL 1024
#define NH 8
#define DHEAD 64
#define HD 512   // NH*DHEAD
#define QKVW 1536
#define CH 64    // chunk length
#define NCH (SEQ / CH)  // 32

typedef float f32x4 __attribute__((ext_vector_type(4)));
typedef short short8 __attribute__((ext_vector_type(8)));
typedef short short4v __attribute__((ext_vector_type(4)));

static __device__ __forceinline__ ushort f2bf(float f) {
  union { float f; unsigned u; } x; x.f = f;
  unsigned r = (x.u + 0x7fffu + ((x.u >> 16) & 1u)) >> 16;
  return (ushort)r;
}
static __device__ __forceinline__ float bf2f(ushort u) {
  union { unsigned u; float f; } x; x.u = ((unsigned)u) << 16;
  return x.f;
}

#define GLDS16(g, l)                                                    \
  __builtin_amdgcn_global_load_lds(                                     \
      (const __attribute__((address_space(1))) unsigned int*)(const void*)(g), \
      (__attribute__((address_space(3))) unsigned int*)(void*)(l), 16, 0, 0)

// ---------------------------------------------------------------------------
// convx: f32 -> bf16 straight copy (x). 16 elems/thread.
// ---------------------------------------------------------------------------
__global__ __launch_bounds__(256) void convx_kernel(
    const float* __restrict__ x, ushort* __restrict__ xb) {
  size_t i = ((size_t)blockIdx.x * 256 + threadIdx.x) * 16;
  ushort t[16];
#pragma unroll
  for (int u = 0; u < 4; ++u) {
    f32x4 v = *(const f32x4*)&x[i + u * 4];
#pragma unroll
    for (int e = 0; e < 4; ++e) t[u * 4 + e] = f2bf(v[e]);
  }
  *(short8*)&xb[i] = *(short8*)&t[0];
  *(short8*)&xb[i + 8] = *(short8*)&t[8];
}

// ---------------------------------------------------------------------------
// convw: transpose + convert weights.
//   blockIdx.y 0..2: Wq/Wk/Wv [1024][512] -> Wt rows [y*512 + n][k]
//   blockIdx.y 3   : Wo [512][1024] -> Wot [n][k]
// ---------------------------------------------------------------------------
__global__ __launch_bounds__(256) void convw_kernel(
    const float* __restrict__ Wq, const float* __restrict__ Wk,
    const float* __restrict__ Wv, const float* __restrict__ Wo,
    ushort* __restrict__ Wt, ushort* __restrict__ Wot) {
  const int m = blockIdx.y;
  const int bx = blockIdx.x;
  const int tid = threadIdx.x;
  __shared__ float T[32][33];

  const float* src;
  ushort* dst;
  int srcN, dstK, k0, n0, rowOff;
  if (m < 3) {
    src = (m == 0) ? Wq : ((m == 1) ? Wk : Wv);
    srcN = 512; dstK = 1024;
    k0 = (bx >> 4) << 5; n0 = (bx & 15) << 5;
    dst = Wt; rowOff = m * 512;
  } else {
    src = Wo; srcN = 1024; dstK = 512;
    k0 = (bx >> 5) << 5; n0 = (bx & 31) << 5;
    dst = Wot; rowOff = 0;
  }
  const int r = tid >> 3, c4 = (tid & 7) << 2;
  f32x4 v = *(const f32x4*)&src[(size_t)(k0 + r) * srcN + n0 + c4];
  T[r][c4 + 0] = v[0]; T[r][c4 + 1] = v[1];
  T[r][c4 + 2] = v[2]; T[r][c4 + 3] = v[3];
  __syncthreads();
  short4v o;
#pragma unroll
  for (int e = 0; e < 4; ++e) o[e] = (short)f2bf(T[c4 + e][r]);
  *(short4v*)&dst[(size_t)(rowOff + n0 + r) * dstK + k0 + c4] = o;
}

// ---------------------------------------------------------------------------
// GEMM: C[M][N] = A[M][K] @ Bt[N][K]^T, bf16 in.  BM=128, BN=256, BK=32,
// 512 threads (8 waves as 2x4), 2-phase dbuf, global_load_lds(16B),
// XCD-aware block swizzle (grid % 8 == 0 required).
// Per thread staging: 1x A-chunk + 2x B-chunk (16B each) per K-step.
// ---------------------------------------------------------------------------
template <bool OUT_BF16>
__global__ __launch_bounds__(512, 4) void gemm_bt_kernel(
    const ushort* __restrict__ A, const ushort* __restrict__ Bt,
    void* __restrict__ Cv, const float* __restrict__ bias,
    int M, int N, int K) {
  const int tiles_n = N >> 8;
  const int nwg = gridDim.x;
  const int bid = blockIdx.x;
  const int swz = (bid & 7) * (nwg >> 3) + (bid >> 3);
  const int bm = swz / tiles_n;
  const int bn = swz % tiles_n;
  const int tid = threadIdx.x;
  const int w = tid >> 6, lane = tid & 63;
  const int wr = w >> 2, wc = w & 3;           // wave tile: rows wr*64, cols wc*64
  const int fr = lane & 15, fq = lane >> 4;

  __shared__ ushort As[2][128][32];   // 16 KB each buf
  __shared__ ushort Bs[2][256][32];   // 32 KB each buf

  f32x4 acc[4][4];
#pragma unroll
  for (int mi = 0; mi < 4; ++mi)
#pragma unroll
    for (int ni = 0; ni < 4; ++ni) acc[mi][ni] = f32x4{0.f, 0.f, 0.f, 0.f};

  // staging addresses: chunk = 16B = 8 bf16
  const int sr = tid >> 2;              // 0..127
  const int sc = (tid & 3) << 3;        // ushort col 0/8/16/24
  const ushort* ga  = A  + (size_t)(bm * 128 + sr) * K + sc;
  const ushort* gb0 = Bt + (size_t)(bn * 256 + sr) * K + sc;
  const ushort* gb1 = Bt + (size_t)(bn * 256 + 128 + sr) * K + sc;

  const int nt = K >> 5;

  {
    ushort* la = &As[0][0][0] + (size_t)tid * 8;
    ushort* lb = &Bs[0][0][0] + (size_t)tid * 8;
    GLDS16(ga, la);
    GLDS16(gb0, lb);
    GLDS16(gb1, lb + 4096);
  }
  asm volatile("s_waitcnt vmcnt(0)" ::: "memory");
  __syncthreads();

  for (int t = 0; t < nt; ++t) {
    if (t + 1 < nt) {
      const int nb = (t + 1) & 1;
      const int kt = (t + 1) << 5;
      ushort* la = &As[nb][0][0] + (size_t)tid * 8;
      ushort* lb = &Bs[nb][0][0] + (size_t)tid * 8;
      GLDS16(ga + kt, la);
      GLDS16(gb0 + kt, lb);
      GLDS16(gb1 + kt, lb + 4096);
    }
    const int cb = t & 1;
    short8 a[4], b[4];
#pragma unroll
    for (int mi = 0; mi < 4; ++mi)
      a[mi] = *(const short8*)&As[cb][wr * 64 + mi * 16 + fr][fq * 8];
#pragma unroll
    for (int ni = 0; ni < 4; ++ni)
      b[ni] = *(const short8*)&Bs[cb][wc * 64 + ni * 16 + fr][fq * 8];
#pragma unroll
    for (int mi = 0; mi < 4; ++mi)
#pragma unroll
      for (int ni = 0; ni < 4; ++ni)
        acc[mi][ni] = __builtin_amdgcn_mfma_f32_16x16x32_bf16(
            a[mi], b[ni], acc[mi][ni], 0, 0, 0);
    asm volatile("s_waitcnt vmcnt(0)" ::: "memory");
    __syncthreads();
  }

  // epilogue: C/D layout col=lane&15, row=(lane>>4)*4+reg
#pragma unroll
  for (int ni = 0; ni < 4; ++ni) {
    const int gc = bn * 256 + wc * 64 + ni * 16 + fr;
    float badd = (!OUT_BF16 && bias) ? bias[gc] : 0.f;
#pragma unroll
    for (int mi = 0; mi < 4; ++mi) {
#pragma unroll
      for (int r = 0; r < 4; ++r) {
        const int gr = bm * 128 + wr * 64 + mi * 16 + fq * 4 + r;
        if (OUT_BF16) {
          ((ushort*)Cv)[(size_t)gr * N + gc] = f2bf(acc[mi][ni][r]);
        } else {
          ((float*)Cv)[(size_t)gr * N + gc] = acc[mi][ni][r] + badd;
        }
      }
    }
  }
}

// ---------------------------------------------------------------------------
// Phase 1 (intra-chunk): reads fused bf16 qkv [M][1536].
//   cum[p] = prod_{r<=p} d ;  P = mask(cum*q @ (v/cum)^T)*ETA (bf16)
//   y_intra = P @ K (bf16 out);  S_c = ETA*cl * K^T @ (V/cum) (bf16 out)
// ---------------------------------------------------------------------------
__global__ __launch_bounds__(256) void intra_kernel(
    const ushort* __restrict__ qkv, const float* __restrict__ gamma,
    ushort* __restrict__ ybf, ushort* __restrict__ S, float* __restrict__ clb) {
  const int bx = blockIdx.x;
  const int c = bx & (NCH - 1);
  const int h = (bx >> 5) & (NH - 1);
  const int b = bx >> 8;
  const int tid = threadIdx.x;
  const int w = tid >> 6, lane = tid & 63;
  const int fr = lane & 15, fq = lane >> 4;

  __shared__ ushort Qs[64][72];
  __shared__ ushort Vs[64][72];
  __shared__ ushort KT[64][72];
  __shared__ ushort VT[64][72];
  __shared__ ushort Ps[64][72];
  __shared__ float cumS[64];
  __shared__ float clS;

  const int p = tid >> 2, d0 = (tid & 3) * 16;
  const ushort* base = &qkv[((size_t)b * SEQ + c * CH + p) * QKVW + h * 64 + d0];
  short8 q0 = *(const short8*)base;
  short8 q1 = *(const short8*)(base + 8);
  short8 k0 = *(const short8*)(base + 512);
  short8 k1 = *(const short8*)(base + 520);
  short8 v0 = *(const short8*)(base + 1024);
  short8 v1 = *(const short8*)(base + 1032);

  if (tid < 64) {
    float g = gamma[(size_t)b * SEQ + c * CH + tid];
    float prod = expf(-fminf(g, 10.f));
#pragma unroll
    for (int off = 1; off < 64; off <<= 1) {
      float o = __shfl_up(prod, off);
      if (tid >= off) prod *= o;
    }
    cumS[tid] = prod;
    if (tid == 63) clS = prod;
  }
  __syncthreads();

  {
    const float cp = cumS[p];
    const float rc = 1.f / cp;
    ushort tq[16], tv[16];
#pragma unroll
    for (int j = 0; j < 8; ++j) {
      tq[j]     = f2bf(bf2f((ushort)q0[j]) * cp);
      tq[8 + j] = f2bf(bf2f((ushort)q1[j]) * cp);
      tv[j]     = f2bf(bf2f((ushort)v0[j]) * rc);
      tv[8 + j] = f2bf(bf2f((ushort)v1[j]) * rc);
      KT[d0 + j][p] = (ushort)k0[j];
      KT[d0 + 8 + j][p] = (ushort)k1[j];
      VT[d0 + j][p] = tv[j];
      VT[d0 + 8 + j][p] = tv[8 + j];
    }
    *(short8*)&Qs[p][d0] = *(short8*)&tq[0];
    *(short8*)&Qs[p][d0 + 8] = *(short8*)&tq[8];
    *(short8*)&Vs[p][d0] = *(short8*)&tv[0];
    *(short8*)&Vs[p][d0 + 8] = *(short8*)&tv[8];
  }
  __syncthreads();

  const int arow = w * 16 + fr;
  {
    short8 a0 = *(const short8*)&Qs[arow][fq * 8];
    short8 a1 = *(const short8*)&Qs[arow][32 + fq * 8];
#pragma unroll
    for (int cf = 0; cf < 4; ++cf) {
      f32x4 acc = {0.f, 0.f, 0.f, 0.f};
      if (cf <= w) {
        short8 b0 = *(const short8*)&Vs[cf * 16 + fr][fq * 8];
        short8 b1 = *(const short8*)&Vs[cf * 16 + fr][32 + fq * 8];
        acc = __builtin_amdgcn_mfma_f32_16x16x32_bf16(a0, b0, acc, 0, 0, 0);
        acc = __builtin_amdgcn_mfma_f32_16x16x32_bf16(a1, b1, acc, 0, 0, 0);
      }
#pragma unroll
      for (int r = 0; r < 4; ++r) {
        int pi = w * 16 + fq * 4 + r, si = cf * 16 + fr;
        Ps[pi][si] = f2bf((si <= pi) ? acc[r] * ETA : 0.f);
      }
    }
  }
  __syncthreads();

  {
    short8 p0 = *(const short8*)&Ps[arow][fq * 8];
    short8 p1 = *(const short8*)&Ps[arow][32 + fq * 8];
    short8 ka0 = *(const short8*)&KT[arow][fq * 8];
    short8 ka1 = *(const short8*)&KT[arow][32 + fq * 8];
    const float scl = ETA * clS;
    const size_t yrow0 = (size_t)b * SEQ + c * CH;
    ushort* Sp = &S[(((size_t)(b * NH + h)) * NCH + c) << 12];
#pragma unroll
    for (int cf = 0; cf < 4; ++cf) {
      short8 bk0 = *(const short8*)&KT[cf * 16 + fr][fq * 8];
      short8 bk1 = *(const short8*)&KT[cf * 16 + fr][32 + fq * 8];
      f32x4 accY = {0.f, 0.f, 0.f, 0.f};
      accY = __builtin_amdgcn_mfma_f32_16x16x32_bf16(p0, bk0, accY, 0, 0, 0);
      accY = __builtin_amdgcn_mfma_f32_16x16x32_bf16(p1, bk1, accY, 0, 0, 0);
      short8 bv0 = *(const short8*)&VT[cf * 16 + fr][fq * 8];
      short8 bv1 = *(const short8*)&VT[cf * 16 + fr][32 + fq * 8];
      f32x4 accS = {0.f, 0.f, 0.f, 0.f};
      accS = __builtin_amdgcn_mfma_f32_16x16x32_bf16(ka0, bv0, accS, 0, 0, 0);
      accS = __builtin_amdgcn_mfma_f32_16x16x32_bf16(ka1, bv1, accS, 0, 0, 0);
#pragma unroll
      for (int r = 0; r < 4; ++r) {
        int row = w * 16 + fq * 4 + r;
        int col = cf * 16 + fr;
        ybf[(yrow0 + row) * HD + h * 64 + col] = f2bf(accY[r]);
        Sp[row * 64 + col] = f2bf(accS[r] * scl);
      }
    }
  }
  if (tid == 0 && h == 0) clb[b * NCH + c] = clS;
}

// ---------------------------------------------------------------------------
// Phase 2: stash[c] = st (before chunk c, bf16); st = cl[c]*st + S_c
// ---------------------------------------------------------------------------
__global__ __launch_bounds__(256) void prop_kernel(
    const float* __restrict__ state0, const ushort* __restrict__ S,
    const float* __restrict__ clb, ushort* __restrict__ stash,
    float* __restrict__ state_out) {
  const int bh = blockIdx.x >> 2, rg = blockIdx.x & 3;
  const int b = bh >> 3;
  const int tid = threadIdx.x;
  const int i = rg * 16 + (tid >> 4);
  const int j0 = (tid & 15) * 4;
  const size_t off = ((size_t)bh * 64 + i) * 64 + j0;
  const size_t coff = (size_t)i * 64 + j0;

  f32x4 st = *(const f32x4*)&state0[off];
#pragma unroll 4
  for (int c = 0; c < NCH; ++c) {
    const size_t base = (((size_t)bh * NCH + c) << 12) + coff;
    short4v sv;
#pragma unroll
    for (int e = 0; e < 4; ++e) sv[e] = (short)f2bf(st[e]);
    *(short4v*)&stash[base] = sv;
    short4v s = *(const short4v*)&S[base];
    float clv = clb[b * NCH + c];
#pragma unroll
    for (int e = 0; e < 4; ++e) st[e] = st[e] * clv + bf2f((ushort)s[e]);
  }
  *(f32x4*)&state_out[off] = st;
}

// ---------------------------------------------------------------------------
// Phase 3: y += (cum*q) @ stash[c]^T   (bf16 RMW on y; stash already bf16)
// ---------------------------------------------------------------------------
__global__ __launch_bounds__(256) void inter_kernel(
    const ushort* __restrict__ qkv, const float* __restrict__ gamma,
    const ushort* __restrict__ stash, ushort* __restrict__ ybf) {
  const int bx = blockIdx.x;
  const int c = bx & (NCH - 1);
  const int h = (bx >> 5) & (NH - 1);
  const int b = bx >> 8;
  const int tid = threadIdx.x;
  const int w = tid >> 6, lane = tid & 63;
  const int fr = lane & 15, fq = lane >> 4;

  __shared__ ushort Qs[64][72];
  __shared__ ushort Bs[64][72];
  __shared__ float cumS[64];

  const int p = tid >> 2, d0 = (tid & 3) * 16;
  const ushort* qp = &qkv[((size_t)b * SEQ + c * CH + p) * QKVW + h * 64 + d0];
  short8 q0 = *(const short8*)qp;
  short8 q1 = *(const short8*)(qp + 8);
  const size_t sb = ((((size_t)(b * NH + h)) * NCH + c) << 12) + (size_t)p * 64 + d0;
  short8 s0 = *(const short8*)&stash[sb];
  short8 s1 = *(const short8*)&stash[sb + 8];

  if (tid < 64) {
    float g = gamma[(size_t)b * SEQ + c * CH + tid];
    float prod = expf(-fminf(g, 10.f));
#pragma unroll
    for (int off = 1; off < 64; off <<= 1) {
      float o = __shfl_up(prod, off);
      if (tid >= off) prod *= o;
    }
    cumS[tid] = prod;
  }
  __syncthreads();

  {
    const float cp = cumS[p];
    ushort tq[16];
#pragma unroll
    for (int j = 0; j < 8; ++j) {
      tq[j]     = f2bf(bf2f((ushort)q0[j]) * cp);
      tq[8 + j] = f2bf(bf2f((ushort)q1[j]) * cp);
    }
    *(short8*)&Qs[p][d0] = *(short8*)&tq[0];
    *(short8*)&Qs[p][d0 + 8] = *(short8*)&tq[8];
    *(short8*)&Bs[p][d0] = s0;
    *(short8*)&Bs[p][d0 + 8] = s1;
  }
  __syncthreads();

  const int arow = w * 16 + fr;
  short8 a0 = *(const short8*)&Qs[arow][fq * 8];
  short8 a1 = *(const short8*)&Qs[arow][32 + fq * 8];
  const size_t yrow0 = (size_t)b * SEQ + c * CH;
#pragma unroll
  for (int cf = 0; cf < 4; ++cf) {
    short8 b0 = *(const short8*)&Bs[cf * 16 + fr][fq * 8];
    short8 b1 = *(const short8*)&Bs[cf * 16 + fr][32 + fq * 8];
    f32x4 acc = {0.f, 0.f, 0.f, 0.f};
    acc = __builtin_amdgcn_mfma_f32_16x16x32_bf16(a0, b0, acc, 0, 0, 0);
    acc = __builtin_amdgcn_mfma_f32_16x16x32_bf16(a1, b1, acc, 0, 0, 0);
#pragma unroll
    for (int r = 0; r < 4; ++r) {
      int row = w * 16 + fq * 4 + r;
      int col = cf * 16 + fr;
      size_t idx = (yrow0 + row) * HD + h * 64 + col;
      ybf[idx] = f2bf(bf2f(ybf[idx]) + acc[r]);
    }
  }
}

extern "C" void kernel_launch(void* const* d_in, const int* in_sizes, int n_in,
                              void* d_out, int out_size, void* d_ws, size_t ws_size,
                              hipStream_t stream) {
  const float* x      = (const float*)d_in[0];
  const float* gamma  = (const float*)d_in[1];
  const float* state0 = (const float*)d_in[2];
  const float* Wq     = (const float*)d_in[3];
  const float* Wk     = (const float*)d_in[4];
  const float* Wv     = (const float*)d_in[5];
  const float* Wo     = (const float*)d_in[6];
  const float* bo     = (const float*)d_in[7];

  float* out = (float*)d_out;
  float* state_out = out + (size_t)BATCH * SEQ * DMODEL;

  const int M = BATCH * SEQ;  // 8192

  ushort* xb  = (ushort*)d_ws;                       // [8192][1024]
  ushort* wt  = xb + (size_t)M * DMODEL;             // [1536][1024]
  ushort* wot = wt + (size_t)QKVW * DMODEL;          // [1024][512]
  ushort* qkv = wot + (size_t)DMODEL * HD;           // [8192][1536]
  ushort* ybf = qkv + (size_t)M * QKVW;              // [8192][512]
  ushort* Sb  = ybf + (size_t)M * HD;                // [32][32][4096] bf16
  ushort* stash = Sb + (size_t)BATCH * NH * NCH * 4096;
  float*  clb   = (float*)(stash + (size_t)BATCH * NH * NCH * 4096);

  dim3 blk(256);
  dim3 blkg(512);

  convx_kernel<<<dim3((M * DMODEL) / (256 * 16)), blk, 0, stream>>>(x, xb);
  convw_kernel<<<dim3(512, 4), blk, 0, stream>>>(Wq, Wk, Wv, Wo, wt, wot);

  gemm_bt_kernel<true><<<dim3((M / 128) * (QKVW / 256)), blkg, 0, stream>>>(
      xb, wt, qkv, nullptr, M, QKVW, DMODEL);

  intra_kernel<<<dim3(BATCH * NH * NCH), blk, 0, stream>>>(
      qkv, gamma, ybf, Sb, clb);
  prop_kernel<<<dim3(BATCH * NH * 4), blk, 0, stream>>>(
      state0, Sb, clb, stash, state_out);
  inter_kernel<<<dim3(BATCH * NH * NCH), blk, 0, stream>>>(
      qkv, gamma, stash, ybf);

  gemm_bt_kernel<false><<<dim3((M / 128) * (DMODEL / 256)), blkg, 0, stream>>>(
      ybf, wot, out, bo, M, DMODEL, HD);
}

// Round 5
// 96.051 us; speedup vs baseline: 8.7182x; 1.0323x over previous
//
#include <hip/hip_runtime.h>

#define ETA 0.1f
#define BATCH 4
#define SEQ 2048
#define DMODEL 1024
#define NH 8
#define DHEAD 64
#define HD 512   // NH*DHEAD
#define QKVW 1536
#define CH 64    // chunk length
#define NCH (SEQ / CH)  // 32

typedef float f32x4 __attribute__((ext_vector_type(4)));
typedef short short8 __attribute__((ext_vector_type(8)));
typedef short short4v __attribute__((ext_vector_type(4)));

static __device__ __forceinline__ ushort f2bf(float f) {
  union { float f; unsigned u; } x; x.f = f;
  unsigned r = (x.u + 0x7fffu + ((x.u >> 16) & 1u)) >> 16;
  return (ushort)r;
}
static __device__ __forceinline__ float bf2f(ushort u) {
  union { unsigned u; float f; } x; x.u = ((unsigned)u) << 16;
  return x.f;
}

#define GLDS16(g, l)                                                    \
  __builtin_amdgcn_global_load_lds(                                     \
      (const __attribute__((address_space(1))) unsigned int*)(const void*)(g), \
      (__attribute__((address_space(3))) unsigned int*)(void*)(l), 16, 0, 0)

// ---------------------------------------------------------------------------
// convx: f32 -> bf16 straight copy (x). 16 elems/thread.
// ---------------------------------------------------------------------------
__global__ __launch_bounds__(256) void convx_kernel(
    const float* __restrict__ x, ushort* __restrict__ xb) {
  size_t i = ((size_t)blockIdx.x * 256 + threadIdx.x) * 16;
  ushort t[16];
#pragma unroll
  for (int u = 0; u < 4; ++u) {
    f32x4 v = *(const f32x4*)&x[i + u * 4];
#pragma unroll
    for (int e = 0; e < 4; ++e) t[u * 4 + e] = f2bf(v[e]);
  }
  *(short8*)&xb[i] = *(short8*)&t[0];
  *(short8*)&xb[i + 8] = *(short8*)&t[8];
}

// ---------------------------------------------------------------------------
// convw: transpose + convert weights.
//   blockIdx.y 0..2: Wq/Wk/Wv [1024][512] -> Wt rows [y*512 + n][k]
//   blockIdx.y 3   : Wo [512][1024] -> Wot [n][k]
// ---------------------------------------------------------------------------
__global__ __launch_bounds__(256) void convw_kernel(
    const float* __restrict__ Wq, const float* __restrict__ Wk,
    const float* __restrict__ Wv, const float* __restrict__ Wo,
    ushort* __restrict__ Wt, ushort* __restrict__ Wot) {
  const int m = blockIdx.y;
  const int bx = blockIdx.x;
  const int tid = threadIdx.x;
  __shared__ float T[32][33];

  const float* src;
  ushort* dst;
  int srcN, dstK, k0, n0, rowOff;
  if (m < 3) {
    src = (m == 0) ? Wq : ((m == 1) ? Wk : Wv);
    srcN = 512; dstK = 1024;
    k0 = (bx >> 4) << 5; n0 = (bx & 15) << 5;
    dst = Wt; rowOff = m * 512;
  } else {
    src = Wo; srcN = 1024; dstK = 512;
    k0 = (bx >> 5) << 5; n0 = (bx & 31) << 5;
    dst = Wot; rowOff = 0;
  }
  const int r = tid >> 3, c4 = (tid & 7) << 2;
  f32x4 v = *(const f32x4*)&src[(size_t)(k0 + r) * srcN + n0 + c4];
  T[r][c4 + 0] = v[0]; T[r][c4 + 1] = v[1];
  T[r][c4 + 2] = v[2]; T[r][c4 + 3] = v[3];
  __syncthreads();
  short4v o;
#pragma unroll
  for (int e = 0; e < 4; ++e) o[e] = (short)f2bf(T[c4 + e][r]);
  *(short4v*)&dst[(size_t)(rowOff + n0 + r) * dstK + k0 + c4] = o;
}

// ---------------------------------------------------------------------------
// GEMM: C[M][N] = A[M][K] @ Bt[N][K]^T, bf16 in.  BM=BN=128, BK=32,
// 256 threads (4 waves, 2x2), 3-buffer pipeline with COUNTED vmcnt
// (T4): loads stay in flight across barriers; no full drain in the loop.
// Grid: (M/128)*(N/128); %8==0 for XCD swizzle.
// Per thread: 4x global_load_lds(16B) per K-step (A:2, B:2).
// ---------------------------------------------------------------------------
template <bool OUT_BF16>
__global__ __launch_bounds__(256, 3) void gemm_bt_kernel(
    const ushort* __restrict__ A, const ushort* __restrict__ Bt,
    void* __restrict__ Cv, const float* __restrict__ bias,
    int M, int N, int K) {
  const int tiles_n = N >> 7;
  const int nwg = gridDim.x;
  const int bid = blockIdx.x;
  const int swz = (bid & 7) * (nwg >> 3) + (bid >> 3);
  const int bm = swz / tiles_n;
  const int bn = swz % tiles_n;
  const int tid = threadIdx.x;
  const int w = tid >> 6, lane = tid & 63;
  const int wr = w >> 1, wc = w & 1;
  const int fr = lane & 15, fq = lane >> 4;

  __shared__ ushort As[3][128][32];   // 8 KB per buf
  __shared__ ushort Bs[3][128][32];   // 8 KB per buf  (total 48 KB)

  f32x4 acc[4][4];
#pragma unroll
  for (int mi = 0; mi < 4; ++mi)
#pragma unroll
    for (int ni = 0; ni < 4; ++ni) acc[mi][ni] = f32x4{0.f, 0.f, 0.f, 0.f};

  const int lw = lane >> 2;            // row within 16-row group
  const int lc = (lane & 3) << 3;      // ushort col (8 bf16 = 16B)
  const ushort* ga = A + (size_t)(bm * 128 + w * 32 + lw) * K + lc;
  const ushort* gb = Bt + (size_t)(bn * 128 + w * 32 + lw) * K + lc;
  const size_t rstep = (size_t)16 * K;

  const int nt = K >> 5;

  // prologue: stage tiles 0,1,2 into bufs 0,1,2 (12 loads in flight/thread)
#pragma unroll
  for (int pt = 0; pt < 3; ++pt) {
    ushort* la = &As[pt][w * 32][0];
    ushort* lb = &Bs[pt][w * 32][0];
    GLDS16(ga + pt * 32, la);
    GLDS16(ga + pt * 32 + rstep, la + 512);
    GLDS16(gb + pt * 32, lb);
    GLDS16(gb + pt * 32 + rstep, lb + 512);
  }

  for (int t = 0; t < nt; ++t) {
    // wait until tile t's 4 loads (per thread) have landed; keep the rest
    // in flight. Fused waitcnt+barrier so the compiler can't add a drain.
    if (t < nt - 2) {
      asm volatile("s_waitcnt vmcnt(8)\n\ts_barrier" ::: "memory");
    } else if (t == nt - 2) {
      asm volatile("s_waitcnt vmcnt(4)\n\ts_barrier" ::: "memory");
    } else {
      asm volatile("s_waitcnt vmcnt(0)\n\ts_barrier" ::: "memory");
    }
    const int cb = t % 3;
    short8 a[4], b[4];
#pragma unroll
    for (int mi = 0; mi < 4; ++mi)
      a[mi] = *(const short8*)&As[cb][wr * 64 + mi * 16 + fr][fq * 8];
#pragma unroll
    for (int ni = 0; ni < 4; ++ni)
      b[ni] = *(const short8*)&Bs[cb][wc * 64 + ni * 16 + fr][fq * 8];
#pragma unroll
    for (int mi = 0; mi < 4; ++mi)
#pragma unroll
      for (int ni = 0; ni < 4; ++ni)
        acc[mi][ni] = __builtin_amdgcn_mfma_f32_16x16x32_bf16(
            a[mi], b[ni], acc[mi][ni], 0, 0, 0);
    // all ds_reads of buf cb drained, then barrier, then safe to overwrite cb
    asm volatile("s_waitcnt lgkmcnt(0)\n\ts_barrier" ::: "memory");
    if (t + 3 < nt) {
      const int kt = (t + 3) << 5;
      ushort* la = &As[cb][w * 32][0];
      ushort* lb = &Bs[cb][w * 32][0];
      GLDS16(ga + kt, la);
      GLDS16(ga + kt + rstep, la + 512);
      GLDS16(gb + kt, lb);
      GLDS16(gb + kt + rstep, lb + 512);
    }
  }

  // epilogue: C/D layout col=lane&15, row=(lane>>4)*4+reg
#pragma unroll
  for (int ni = 0; ni < 4; ++ni) {
    const int gc = bn * 128 + wc * 64 + ni * 16 + fr;
    float badd = (!OUT_BF16 && bias) ? bias[gc] : 0.f;
#pragma unroll
    for (int mi = 0; mi < 4; ++mi) {
#pragma unroll
      for (int r = 0; r < 4; ++r) {
        const int gr = bm * 128 + wr * 64 + mi * 16 + fq * 4 + r;
        if (OUT_BF16) {
          ((ushort*)Cv)[(size_t)gr * N + gc] = f2bf(acc[mi][ni][r]);
        } else {
          ((float*)Cv)[(size_t)gr * N + gc] = acc[mi][ni][r] + badd;
        }
      }
    }
  }
}

// ---------------------------------------------------------------------------
// Phase 1 (intra-chunk): reads fused bf16 qkv [M][1536].
//   cum[p] = prod_{r<=p} d ;  P = mask(cum*q @ (v/cum)^T)*ETA (bf16)
//   y_intra = P @ K (bf16 out);  S_c = ETA*cl * K^T @ (V/cum) (bf16 out)
// ---------------------------------------------------------------------------
__global__ __launch_bounds__(256) void intra_kernel(
    const ushort* __restrict__ qkv, const float* __restrict__ gamma,
    ushort* __restrict__ ybf, ushort* __restrict__ S, float* __restrict__ clb) {
  const int bx = blockIdx.x;
  const int c = bx & (NCH - 1);
  const int h = (bx >> 5) & (NH - 1);
  const int b = bx >> 8;
  const int tid = threadIdx.x;
  const int w = tid >> 6, lane = tid & 63;
  const int fr = lane & 15, fq = lane >> 4;

  __shared__ ushort Qs[64][72];
  __shared__ ushort Vs[64][72];
  __shared__ ushort KT[64][72];
  __shared__ ushort VT[64][72];
  __shared__ ushort Ps[64][72];
  __shared__ float cumS[64];
  __shared__ float clS;

  const int p = tid >> 2, d0 = (tid & 3) * 16;
  const ushort* base = &qkv[((size_t)b * SEQ + c * CH + p) * QKVW + h * 64 + d0];
  short8 q0 = *(const short8*)base;
  short8 q1 = *(const short8*)(base + 8);
  short8 k0 = *(const short8*)(base + 512);
  short8 k1 = *(const short8*)(base + 520);
  short8 v0 = *(const short8*)(base + 1024);
  short8 v1 = *(const short8*)(base + 1032);

  if (tid < 64) {
    float g = gamma[(size_t)b * SEQ + c * CH + tid];
    float prod = expf(-fminf(g, 10.f));
#pragma unroll
    for (int off = 1; off < 64; off <<= 1) {
      float o = __shfl_up(prod, off);
      if (tid >= off) prod *= o;
    }
    cumS[tid] = prod;
    if (tid == 63) clS = prod;
  }
  __syncthreads();

  {
    const float cp = cumS[p];
    const float rc = 1.f / cp;
    ushort tq[16], tv[16];
#pragma unroll
    for (int j = 0; j < 8; ++j) {
      tq[j]     = f2bf(bf2f((ushort)q0[j]) * cp);
      tq[8 + j] = f2bf(bf2f((ushort)q1[j]) * cp);
      tv[j]     = f2bf(bf2f((ushort)v0[j]) * rc);
      tv[8 + j] = f2bf(bf2f((ushort)v1[j]) * rc);
      KT[d0 + j][p] = (ushort)k0[j];
      KT[d0 + 8 + j][p] = (ushort)k1[j];
      VT[d0 + j][p] = tv[j];
      VT[d0 + 8 + j][p] = tv[8 + j];
    }
    *(short8*)&Qs[p][d0] = *(short8*)&tq[0];
    *(short8*)&Qs[p][d0 + 8] = *(short8*)&tq[8];
    *(short8*)&Vs[p][d0] = *(short8*)&tv[0];
    *(short8*)&Vs[p][d0 + 8] = *(short8*)&tv[8];
  }
  __syncthreads();

  const int arow = w * 16 + fr;
  {
    short8 a0 = *(const short8*)&Qs[arow][fq * 8];
    short8 a1 = *(const short8*)&Qs[arow][32 + fq * 8];
#pragma unroll
    for (int cf = 0; cf < 4; ++cf) {
      f32x4 acc = {0.f, 0.f, 0.f, 0.f};
      if (cf <= w) {
        short8 b0 = *(const short8*)&Vs[cf * 16 + fr][fq * 8];
        short8 b1 = *(const short8*)&Vs[cf * 16 + fr][32 + fq * 8];
        acc = __builtin_amdgcn_mfma_f32_16x16x32_bf16(a0, b0, acc, 0, 0, 0);
        acc = __builtin_amdgcn_mfma_f32_16x16x32_bf16(a1, b1, acc, 0, 0, 0);
      }
#pragma unroll
      for (int r = 0; r < 4; ++r) {
        int pi = w * 16 + fq * 4 + r, si = cf * 16 + fr;
        Ps[pi][si] = f2bf((si <= pi) ? acc[r] * ETA : 0.f);
      }
    }
  }
  __syncthreads();

  {
    short8 p0 = *(const short8*)&Ps[arow][fq * 8];
    short8 p1 = *(const short8*)&Ps[arow][32 + fq * 8];
    short8 ka0 = *(const short8*)&KT[arow][fq * 8];
    short8 ka1 = *(const short8*)&KT[arow][32 + fq * 8];
    const float scl = ETA * clS;
    const size_t yrow0 = (size_t)b * SEQ + c * CH;
    ushort* Sp = &S[(((size_t)(b * NH + h)) * NCH + c) << 12];
#pragma unroll
    for (int cf = 0; cf < 4; ++cf) {
      short8 bk0 = *(const short8*)&KT[cf * 16 + fr][fq * 8];
      short8 bk1 = *(const short8*)&KT[cf * 16 + fr][32 + fq * 8];
      f32x4 accY = {0.f, 0.f, 0.f, 0.f};
      accY = __builtin_amdgcn_mfma_f32_16x16x32_bf16(p0, bk0, accY, 0, 0, 0);
      accY = __builtin_amdgcn_mfma_f32_16x16x32_bf16(p1, bk1, accY, 0, 0, 0);
      short8 bv0 = *(const short8*)&VT[cf * 16 + fr][fq * 8];
      short8 bv1 = *(const short8*)&VT[cf * 16 + fr][32 + fq * 8];
      f32x4 accS = {0.f, 0.f, 0.f, 0.f};
      accS = __builtin_amdgcn_mfma_f32_16x16x32_bf16(ka0, bv0, accS, 0, 0, 0);
      accS = __builtin_amdgcn_mfma_f32_16x16x32_bf16(ka1, bv1, accS, 0, 0, 0);
#pragma unroll
      for (int r = 0; r < 4; ++r) {
        int row = w * 16 + fq * 4 + r;
        int col = cf * 16 + fr;
        ybf[(yrow0 + row) * HD + h * 64 + col] = f2bf(accY[r]);
        Sp[row * 64 + col] = f2bf(accS[r] * scl);
      }
    }
  }
  if (tid == 0 && h == 0) clb[b * NCH + c] = clS;
}

// ---------------------------------------------------------------------------
// Phase 2: stash[c] = st (before chunk c, bf16); st = cl[c]*st + S_c
// ---------------------------------------------------------------------------
__global__ __launch_bounds__(256) void prop_kernel(
    const float* __restrict__ state0, const ushort* __restrict__ S,
    const float* __restrict__ clb, ushort* __restrict__ stash,
    float* __restrict__ state_out) {
  const int bh = blockIdx.x >> 2, rg = blockIdx.x & 3;
  const int b = bh >> 3;
  const int tid = threadIdx.x;
  const int i = rg * 16 + (tid >> 4);
  const int j0 = (tid & 15) * 4;
  const size_t off = ((size_t)bh * 64 + i) * 64 + j0;
  const size_t coff = (size_t)i * 64 + j0;

  f32x4 st = *(const f32x4*)&state0[off];
#pragma unroll 4
  for (int c = 0; c < NCH; ++c) {
    const size_t base = (((size_t)bh * NCH + c) << 12) + coff;
    short4v sv;
#pragma unroll
    for (int e = 0; e < 4; ++e) sv[e] = (short)f2bf(st[e]);
    *(short4v*)&stash[base] = sv;
    short4v s = *(const short4v*)&S[base];
    float clv = clb[b * NCH + c];
#pragma unroll
    for (int e = 0; e < 4; ++e) st[e] = st[e] * clv + bf2f((ushort)s[e]);
  }
  *(f32x4*)&state_out[off] = st;
}

// ---------------------------------------------------------------------------
// Phase 3: y += (cum*q) @ stash[c]^T   (bf16 RMW on y; stash already bf16)
// ---------------------------------------------------------------------------
__global__ __launch_bounds__(256) void inter_kernel(
    const ushort* __restrict__ qkv, const float* __restrict__ gamma,
    const ushort* __restrict__ stash, ushort* __restrict__ ybf) {
  const int bx = blockIdx.x;
  const int c = bx & (NCH - 1);
  const int h = (bx >> 5) & (NH - 1);
  const int b = bx >> 8;
  const int tid = threadIdx.x;
  const int w = tid >> 6, lane = tid & 63;
  const int fr = lane & 15, fq = lane >> 4;

  __shared__ ushort Qs[64][72];
  __shared__ ushort Bs[64][72];
  __shared__ float cumS[64];

  const int p = tid >> 2, d0 = (tid & 3) * 16;
  const ushort* qp = &qkv[((size_t)b * SEQ + c * CH + p) * QKVW + h * 64 + d0];
  short8 q0 = *(const short8*)qp;
  short8 q1 = *(const short8*)(qp + 8);
  const size_t sb = ((((size_t)(b * NH + h)) * NCH + c) << 12) + (size_t)p * 64 + d0;
  short8 s0 = *(const short8*)&stash[sb];
  short8 s1 = *(const short8*)&stash[sb + 8];

  if (tid < 64) {
    float g = gamma[(size_t)b * SEQ + c * CH + tid];
    float prod = expf(-fminf(g, 10.f));
#pragma unroll
    for (int off = 1; off < 64; off <<= 1) {
      float o = __shfl_up(prod, off);
      if (tid >= off) prod *= o;
    }
    cumS[tid] = prod;
  }
  __syncthreads();

  {
    const float cp = cumS[p];
    ushort tq[16];
#pragma unroll
    for (int j = 0; j < 8; ++j) {
      tq[j]     = f2bf(bf2f((ushort)q0[j]) * cp);
      tq[8 + j] = f2bf(bf2f((ushort)q1[j]) * cp);
    }
    *(short8*)&Qs[p][d0] = *(short8*)&tq[0];
    *(short8*)&Qs[p][d0 + 8] = *(short8*)&tq[8];
    *(short8*)&Bs[p][d0] = s0;
    *(short8*)&Bs[p][d0 + 8] = s1;
  }
  __syncthreads();

  const int arow = w * 16 + fr;
  short8 a0 = *(const short8*)&Qs[arow][fq * 8];
  short8 a1 = *(const short8*)&Qs[arow][32 + fq * 8];
  const size_t yrow0 = (size_t)b * SEQ + c * CH;
#pragma unroll
  for (int cf = 0; cf < 4; ++cf) {
    short8 b0 = *(const short8*)&Bs[cf * 16 + fr][fq * 8];
    short8 b1 = *(const short8*)&Bs[cf * 16 + fr][32 + fq * 8];
    f32x4 acc = {0.f, 0.f, 0.f, 0.f};
    acc = __builtin_amdgcn_mfma_f32_16x16x32_bf16(a0, b0, acc, 0, 0, 0);
    acc = __builtin_amdgcn_mfma_f32_16x16x32_bf16(a1, b1, acc, 0, 0, 0);
#pragma unroll
    for (int r = 0; r < 4; ++r) {
      int row = w * 16 + fq * 4 + r;
      int col = cf * 16 + fr;
      size_t idx = (yrow0 + row) * HD + h * 64 + col;
      ybf[idx] = f2bf(bf2f(ybf[idx]) + acc[r]);
    }
  }
}

extern "C" void kernel_launch(void* const* d_in, const int* in_sizes, int n_in,
                              void* d_out, int out_size, void* d_ws, size_t ws_size,
                              hipStream_t stream) {
  const float* x      = (const float*)d_in[0];
  const float* gamma  = (const float*)d_in[1];
  const float* state0 = (const float*)d_in[2];
  const float* Wq     = (const float*)d_in[3];
  const float* Wk     = (const float*)d_in[4];
  const float* Wv     = (const float*)d_in[5];
  const float* Wo     = (const float*)d_in[6];
  const float* bo     = (const float*)d_in[7];

  float* out = (float*)d_out;
  float* state_out = out + (size_t)BATCH * SEQ * DMODEL;

  const int M = BATCH * SEQ;  // 8192

  ushort* xb  = (ushort*)d_ws;                       // [8192][1024]
  ushort* wt  = xb + (size_t)M * DMODEL;             // [1536][1024]
  ushort* wot = wt + (size_t)QKVW * DMODEL;          // [1024][512]
  ushort* qkv = wot + (size_t)DMODEL * HD;           // [8192][1536]
  ushort* ybf = qkv + (size_t)M * QKVW;              // [8192][512]
  ushort* Sb  = ybf + (size_t)M * HD;                // [32][32][4096] bf16
  ushort* stash = Sb + (size_t)BATCH * NH * NCH * 4096;
  float*  clb   = (float*)(stash + (size_t)BATCH * NH * NCH * 4096);

  dim3 blk(256);

  convx_kernel<<<dim3((M * DMODEL) / (256 * 16)), blk, 0, stream>>>(x, xb);
  convw_kernel<<<dim3(512, 4), blk, 0, stream>>>(Wq, Wk, Wv, Wo, wt, wot);

  gemm_bt_kernel<true><<<dim3((M / 128) * (QKVW / 128)), blk, 0, stream>>>(
      xb, wt, qkv, nullptr, M, QKVW, DMODEL);

  intra_kernel<<<dim3(BATCH * NH * NCH), blk, 0, stream>>>(
      qkv, gamma, ybf, Sb, clb);
  prop_kernel<<<dim3(BATCH * NH * 4), blk, 0, stream>>>(
      state0, Sb, clb, stash, state_out);
  inter_kernel<<<dim3(BATCH * NH * NCH), blk, 0, stream>>>(
      qkv, gamma, stash, ybf);

  gemm_bt_kernel<false><<<dim3((M / 128) * (DMODEL / 128)), blk, 0, stream>>>(
      ybf, wot, out, bo, M, DMODEL, HD);
}